// Round 11
// baseline (1030.612 us; speedup 1.0000x reference)
//
#include <hip/hip_runtime.h>
#include <hip/hip_cooperative_groups.h>
#include <hip/hip_bf16.h>
#include <math.h>

namespace cg = cooperative_groups;

#define NDIM 2048
#define EDIM 5
#define CDIM 2
#define WIN 256
#define WOUT 128
#define NCLS 8
#define NTGT 1024
#define NN ((size_t)NDIM * NDIM)
#define HNSC 256.0f
#define HNSCI 0.00390625f
#define GRID 512

typedef __attribute__((ext_vector_type(8))) short short8v;
typedef __attribute__((ext_vector_type(4))) float float4v;
typedef __attribute__((ext_vector_type(8))) int int8v;
typedef __attribute__((ext_vector_type(4))) int int4v;
typedef __attribute__((ext_vector_type(2))) int int2v;

__device__ __forceinline__ void gl2lds16(const void* g, void* l) {
  __builtin_amdgcn_global_load_lds((__attribute__((address_space(1))) const unsigned int*)g,
                                   (__attribute__((address_space(3))) unsigned int*)l, 16, 0, 0);
}
__device__ __forceinline__ float bf2f(unsigned short u) {
  return __uint_as_float(((unsigned)u) << 16);
}
__device__ __forceinline__ unsigned short f2bf(float f) {
  __hip_bfloat16 h = __float2bfloat16(f);
  return *(unsigned short*)&h;
}
__device__ __forceinline__ unsigned int pk4fp8(float a, float b, float c, float d) {
  int w = __builtin_amdgcn_cvt_pk_fp8_f32(a, b, 0, false);
  return (unsigned int)__builtin_amdgcn_cvt_pk_fp8_f32(c, d, w, true);
}

#define N_XBF (NDIM * WIN)
#define N_WT (WIN * WOUT)
#define N_W12T (384 * WIN)
#define N_PREP (N_XBF + N_WT + N_W12T + CDIM * NDIM + 16 + 30)
#define N_PREPB ((N_PREP + 255) / 256)   // 2577

// ---------------------------------------------------------------------------
// fp8 GEMM body (MX unit scale, B^T input, 128x128 tile, BK=128, swizzled,
// single-buffered 32 KB LDS). cs: diag-excluded column sums (atomicAdd).
// ---------------------------------------------------------------------------
__device__ void fp8_gemm_body(
    const unsigned char* __restrict__ A, const unsigned char* __restrict__ B,
    __hip_bfloat16* __restrict__ Cp, float* __restrict__ csp,
    int K, int ldc, int row0, int col0,
    unsigned char* As, unsigned char* Bs) {
  const int tid = threadIdx.x;
  const int lane = tid & 63;
  const int wave = tid >> 6;
  const int wr = (wave >> 1) * 64;
  const int wc = (wave & 1) * 64;
  const int q = lane >> 4;
  const int r = lane & 15;

  float4v acc[4][4] = {};

  const int srow = lane >> 3;
  const int scol = ((lane & 7) ^ (srow & 7)) * 16;
  const int fsw = r & 7;

  for (int k0 = 0; k0 < K; k0 += 128) {
    __syncthreads();
#pragma unroll
    for (int s = 0; s < 4; ++s) {
      gl2lds16(A + (size_t)(row0 + s * 32 + wave * 8 + srow) * K + k0 + scol,
               As + s * 4096 + wave * 1024);
      gl2lds16(B + (size_t)(col0 + s * 32 + wave * 8 + srow) * K + k0 + scol,
               Bs + s * 4096 + wave * 1024);
    }
    __syncthreads();

    union { int8v v; int4v h[2]; } ua[4], ub[4];
#pragma unroll
    for (int i = 0; i < 4; ++i) {
      const unsigned char* pa = As + (size_t)(wr + i * 16 + r) * 128;
      const unsigned char* pb = Bs + (size_t)(wc + i * 16 + r) * 128;
      ua[i].h[0] = *(const int4v*)(pa + (((2 * q) ^ fsw) * 16));
      ua[i].h[1] = *(const int4v*)(pa + (((2 * q + 1) ^ fsw) * 16));
      ub[i].h[0] = *(const int4v*)(pb + (((2 * q) ^ fsw) * 16));
      ub[i].h[1] = *(const int4v*)(pb + (((2 * q + 1) ^ fsw) * 16));
    }
#pragma unroll
    for (int i = 0; i < 4; ++i)
#pragma unroll
      for (int j = 0; j < 4; ++j)
        acc[i][j] = __builtin_amdgcn_mfma_scale_f32_16x16x128_f8f6f4(
            ua[i].v, ub[j].v, acc[i][j], 0, 0, 0, 0x7F7F7F7F, 0, 0x7F7F7F7F);
  }

#pragma unroll
  for (int i = 0; i < 4; ++i) {
    int row = row0 + wr + i * 16 + q * 4;
#pragma unroll
    for (int j = 0; j < 4; ++j) {
      int col = col0 + wc + j * 16 + r;
#pragma unroll
      for (int e = 0; e < 4; ++e)
        Cp[(size_t)(row + e) * ldc + col] = __float2bfloat16(acc[i][j][e]);
    }
  }

  if (csp) {
#pragma unroll
    for (int j = 0; j < 4; ++j) {
      int col = col0 + wc + j * 16 + r;
      float s = 0.f;
#pragma unroll
      for (int i = 0; i < 4; ++i) {
        int rowb = row0 + wr + i * 16 + q * 4;
#pragma unroll
        for (int e = 0; e < 4; ++e)
          if (rowb + e != col) s += acc[i][j][e];
      }
      s += __shfl_xor(s, 16, 64);
      s += __shfl_xor(s, 32, 64);
      if (lane < 16) atomicAdd(&csp[col], s);
    }
  }
}

// ---------------------------------------------------------------------------
// bf16 GEMM body (B^T input, 128x128 tile, BK=64, swizzled, bf16 out)
// ---------------------------------------------------------------------------
__device__ void bf16_gemm_body(
    const __hip_bfloat16* __restrict__ A, const __hip_bfloat16* __restrict__ B,
    __hip_bfloat16* __restrict__ Cp, int K, int ldc, int row0, int col0,
    int kbeg, int kend, char* As, char* Bs) {
  const int tid = threadIdx.x;
  const int lane = tid & 63;
  const int wave = tid >> 6;
  const int wr = (wave >> 1) * 64;
  const int wc = (wave & 1) * 64;
  const int q = lane >> 4;
  const int r = lane & 15;

  float4v acc[4][4] = {};

  const int srow = lane >> 3;
  const int scol = ((lane & 7) ^ (srow & 7)) * 8;
  const int fsw = r & 7;

  for (int k0 = kbeg; k0 < kend; k0 += 64) {
    __syncthreads();
#pragma unroll
    for (int s = 0; s < 4; ++s) {
      gl2lds16(A + (size_t)(row0 + s * 32 + wave * 8 + srow) * K + k0 + scol,
               As + s * 4096 + wave * 1024);
      gl2lds16(B + (size_t)(col0 + s * 32 + wave * 8 + srow) * K + k0 + scol,
               Bs + s * 4096 + wave * 1024);
    }
    __syncthreads();
#pragma unroll
    for (int h = 0; h < 2; ++h) {
      short8v af[4], bf[4];
#pragma unroll
      for (int i = 0; i < 4; ++i) {
        af[i] = *(const short8v*)(As + (size_t)(wr + i * 16 + r) * 128 +
                                  (((h * 4 + q) ^ fsw) * 16));
        bf[i] = *(const short8v*)(Bs + (size_t)(wc + i * 16 + r) * 128 +
                                  (((h * 4 + q) ^ fsw) * 16));
      }
#pragma unroll
      for (int i = 0; i < 4; ++i)
#pragma unroll
        for (int j = 0; j < 4; ++j)
          acc[i][j] = __builtin_amdgcn_mfma_f32_16x16x32_bf16(af[i], bf[j], acc[i][j], 0, 0, 0);
    }
  }

#pragma unroll
  for (int i = 0; i < 4; ++i) {
    int row = row0 + wr + i * 16 + q * 4;
#pragma unroll
    for (int j = 0; j < 4; ++j) {
      int col = col0 + wc + j * 16 + r;
#pragma unroll
      for (int e = 0; e < 4; ++e)
        Cp[(size_t)(row + e) * ldc + col] = __float2bfloat16(acc[i][j][e]);
    }
  }
}

// ---------------------------------------------------------------------------
// phase_exec: one virtual block of one phase. Shared by the cooperative
// mega-kernel (looped) and the fallback per-phase launches.
// ---------------------------------------------------------------------------
__device__ void phase_exec(
    int ph, int vb, unsigned char* smem,
    const float* __restrict__ A, const float* __restrict__ X,
    const float* __restrict__ W, const float* __restrict__ W1,
    const float* __restrict__ W2, const float* __restrict__ linw,
    const float* __restrict__ linb, const float* __restrict__ w0a,
    const float* __restrict__ w0b, const float* __restrict__ w1a,
    const int* __restrict__ txs, const int* __restrict__ tgt,
    float* __restrict__ dout, float* __restrict__ ws) {
  const int tid = threadIdx.x;
  unsigned char* wb = (unsigned char*)ws;
  unsigned char* P_a   = wb;
  unsigned char* P_bT  = wb + 2 * NN;
  unsigned char* P_a1T = wb + 4 * NN;
  unsigned char* P_Hn  = wb + 6 * NN;
  __hip_bfloat16* H_bf   = (__hip_bfloat16*)(ws + 2 * NN);
  __hip_bfloat16* H1T_bf = (__hip_bfloat16*)(ws + 3 * NN);
  __hip_bfloat16* Hn2T   = (__hip_bfloat16*)(ws + 4 * NN);
  __hip_bfloat16* HsT    = (__hip_bfloat16*)(ws);
  float* sm = ws + 5 * NN;
  float* acc = sm;                sm += 16;
  float* deg = sm;                sm += CDIM * NDIM;
  __hip_bfloat16* Xbf    = (__hip_bfloat16*)sm;  sm += N_XBF / 2;
  __hip_bfloat16* WTbf   = (__hip_bfloat16*)sm;  sm += N_WT / 2;
  __hip_bfloat16* W12Tbf = (__hip_bfloat16*)sm;  sm += N_W12T / 2;
  __hip_bfloat16* XWT    = (__hip_bfloat16*)sm;  sm += (size_t)WOUT * NDIM / 2;
  __hip_bfloat16* Xcat   = (__hip_bfloat16*)sm;  sm += (size_t)NDIM * 256 / 2;
  __hip_bfloat16* XC12T  = (__hip_bfloat16*)sm;  sm += (size_t)384 * NDIM / 2;
  __hip_bfloat16* P7bf   = (__hip_bfloat16*)sm;  sm += (size_t)16 * 262144 / 2;
  __hip_bfloat16* P10bf  = (__hip_bfloat16*)sm;  sm += (size_t)8 * 786432 / 2;

  switch (ph) {
    case 0: {  // wsum tiles (vb<4096) + prep
      if (vb >= 4096) {
        int idx = (vb - 4096) * 256 + tid;
        if (idx < N_XBF) { Xbf[idx] = __float2bfloat16(X[idx]); break; }
        idx -= N_XBF;
        if (idx < N_WT) {
          int d = idx >> 8, k = idx & 255;
          WTbf[idx] = __float2bfloat16(W[k * WOUT + d]);
          break;
        }
        idx -= N_WT;
        if (idx < N_W12T) {
          int j = idx >> 8, k = idx & 255;
          W12Tbf[idx] = __float2bfloat16(j < 128 ? W1[k * 128 + j] : W2[k * 256 + (j - 128)]);
          break;
        }
        idx -= N_W12T;
        if (idx < CDIM * NDIM) { deg[idx] = 0.f; break; }
        idx -= CDIM * NDIM;
        if (idx < 16) { acc[idx] = 0.f; break; }
        idx -= 16;
        if (idx < 30) {
          int m = idx / 10, rr = idx - m * 10, c = rr / 5, e = rr - c * 5;
          const float* src = (m == 0) ? w0a : (m == 1) ? w0b : w1a;
          float mx = -1e30f;
          for (int t = 0; t < 5; ++t) mx = fmaxf(mx, src[c * 5 + t]);
          float s = 0.f, ve = 0.f;
          for (int t = 0; t < 5; ++t) {
            float ex = expf(src[c * 5 + t] - mx);
            s += ex;
            if (t == e) ve = ex;
          }
          dout[1 + NTGT * NCLS + idx] = ve / s;
        }
        break;
      }
      float* swl = (float*)smem;                    // 32 f
      float (*tb)[32][33] = (float(*)[32][33])(smem + 128);
      float (*tc)[32][33] = (float(*)[32][33])(smem + 128 + 8448);
      if (tid < 6) {
        int m = tid >> 1, c = tid & 1;
        const float* src = (m == 0) ? w0a : (m == 1) ? w0b : w1a;
        float mx = -1e30f;
        for (int e = 0; e < 5; ++e) mx = fmaxf(mx, src[c * 5 + e]);
        float ex[5]; float s = 0.f;
        for (int e = 0; e < 5; ++e) { ex[e] = expf(src[c * 5 + e] - mx); s += ex[e]; }
        for (int e = 0; e < 5; ++e) swl[m * 10 + c * 5 + e] = ex[e] / s;
      }
      __syncthreads();
      const int bx = (vb & 63) * 32, by = (vb >> 6) * 32;
      const int tx4 = tid & 7, ty = tid >> 3;
      const int n = by + ty, m0 = bx + tx4 * 4;
      const float* ap = A + ((size_t)n * NDIM + m0) * EDIM;
      float4 f0 = *(const float4*)(ap);
      float4 f1 = *(const float4*)(ap + 4);
      float4 f2 = *(const float4*)(ap + 8);
      float4 f3 = *(const float4*)(ap + 12);
      float4 f4 = *(const float4*)(ap + 16);
      float v[4][5] = {{f0.x, f0.y, f0.z, f0.w, f1.x},
                       {f1.y, f1.z, f1.w, f2.x, f2.y},
                       {f2.z, f2.w, f3.x, f3.y, f3.z},
                       {f3.w, f4.x, f4.y, f4.z, f4.w}};
#pragma unroll
      for (int c = 0; c < CDIM; ++c) {
        float sa[4];
#pragma unroll
        for (int t = 0; t < 4; ++t) {
          sa[t] = swl[c*5]*v[t][0] + swl[c*5+1]*v[t][1] + swl[c*5+2]*v[t][2] +
                  swl[c*5+3]*v[t][3] + swl[c*5+4]*v[t][4];
          tb[c][ty][tx4 * 4 + t] =
              swl[10+c*5]*v[t][0] + swl[10+c*5+1]*v[t][1] + swl[10+c*5+2]*v[t][2] +
              swl[10+c*5+3]*v[t][3] + swl[10+c*5+4]*v[t][4];
          tc[c][ty][tx4 * 4 + t] =
              swl[20+c*5]*v[t][0] + swl[20+c*5+1]*v[t][1] + swl[20+c*5+2]*v[t][2] +
              swl[20+c*5+3]*v[t][3] + swl[20+c*5+4]*v[t][4];
        }
        *(unsigned int*)(P_a + c * NN + (size_t)n * NDIM + m0) =
            pk4fp8(sa[0], sa[1], sa[2], sa[3]);
      }
      __syncthreads();
      const int mm = bx + ty, nn0 = by + tx4 * 4;
#pragma unroll
      for (int c = 0; c < CDIM; ++c) {
        *(unsigned int*)(P_bT + c * NN + (size_t)mm * NDIM + nn0) =
            pk4fp8(tb[c][tx4*4+0][ty], tb[c][tx4*4+1][ty],
                   tb[c][tx4*4+2][ty], tb[c][tx4*4+3][ty]);
        *(unsigned int*)(P_a1T + c * NN + (size_t)mm * NDIM + nn0) =
            pk4fp8(tc[c][tx4*4+0][ty], tc[c][tx4*4+1][ty],
                   tc[c][tx4*4+2][ty], tc[c][tx4*4+3][ty]);
      }
      __syncthreads();  // smem reused next virtual block
      break;
    }
    case 1: {  // GEMM1 (512) + XWT (16)
      if (vb < 512) {
        int c = vb >> 8, x = vb & 15, y = (vb >> 4) & 15;
        fp8_gemm_body(P_a + (size_t)c * NN, P_bT + (size_t)c * NN,
                      H_bf + (size_t)c * NN, deg + (size_t)c * NDIM,
                      NDIM, NDIM, y * 128, x * 128, smem, smem + 16384);
      } else {
        int x = vb - 512;
        bf16_gemm_body(WTbf, Xbf, XWT, WIN, NDIM, 0, x * 128, 0, WIN,
                       (char*)smem, (char*)smem + 16384);
      }
      break;
    }
    case 2: {  // col_scale: Hn*HNSC fp8
      size_t base = ((size_t)vb * 256 + tid) * 8;
      int c = (int)(base >> 22);
      int i = (int)((base >> 11) & (NDIM - 1));
      int j0 = (int)(base & (NDIM - 1));
      union { short8v v; unsigned short u[8]; } p;
      p.v = *(const short8v*)(H_bf + base);
      float f[8];
#pragma unroll
      for (int t = 0; t < 8; ++t) {
        int j = j0 + t;
        float d = deg[c * NDIM + j];
        float inv = (d == 0.f) ? 0.f : HNSC / d;
        float vv = (i == j) ? 0.f : bf2f(p.u[t]);
        f[t] = vv * inv;
      }
      int2v o;
      o.x = (int)pk4fp8(f[0], f[1], f[2], f[3]);
      o.y = (int)pk4fp8(f[4], f[5], f[6], f[7]);
      *(int2v*)(P_Hn + base) = o;
      break;
    }
    case 3: {  // GEMM2
      int c = vb >> 8, x = vb & 15, y = (vb >> 4) & 15;
      fp8_gemm_body(P_a1T + (size_t)c * NN, P_Hn + (size_t)c * NN,
                    H1T_bf + (size_t)c * NN, nullptr,
                    NDIM, NDIM, y * 128, x * 128, smem, smem + 16384);
      break;
    }
    case 4: {  // rowmega
      const int m = vb;
      float* ds = (float*)smem;        // 2
      float* red = (float*)smem + 2;   // 8  [ch][4]
      float* bc = (float*)smem + 10;   // 3
      const size_t rb = (size_t)m * NDIM + tid * 8;
      union { short8v v; unsigned short u[8]; } a0, a1;
      a0.v = *(const short8v*)(H1T_bf + rb);
      a1.v = *(const short8v*)(H1T_bf + NN + rb);
      float v0[8], v1[8];
      float s0 = 0.f, s1 = 0.f;
#pragma unroll
      for (int t = 0; t < 8; ++t) {
        v0[t] = bf2f(a0.u[t]) * HNSCI;
        v1[t] = bf2f(a1.u[t]) * HNSCI;
        s0 += v0[t]; s1 += v1[t];
      }
      if (tid == (m >> 3)) { ds[0] = v0[m & 7]; ds[1] = v1[m & 7]; }
      for (int off = 32; off > 0; off >>= 1) {
        s0 += __shfl_down(s0, off, 64);
        s1 += __shfl_down(s1, off, 64);
      }
      if ((tid & 63) == 0) { red[tid >> 6] = s0; red[4 + (tid >> 6)] = s1; }
      __syncthreads();
      if (tid == 0) {
        float t0 = red[0] + red[1] + red[2] + red[3];
        float t1 = red[4] + red[5] + red[6] + red[7];
        float r0 = t0 - ds[0] + 1.f;
        float r1 = t1 - ds[1] + 1.f;
        float rs = t0 + t1 - ds[0] - ds[1] + 1.f;
        bc[0] = (r0 == 0.f) ? 0.f : 1.f / r0;
        bc[1] = (r1 == 0.f) ? 0.f : 1.f / r1;
        bc[2] = (rs == 0.f) ? 0.f : 1.f / rs;
      }
      __syncthreads();
      float i0 = bc[0], i1 = bc[1], is = bc[2];
      union { short8v v; unsigned short u[8]; } o0, o1, os;
#pragma unroll
      for (int t = 0; t < 8; ++t) {
        bool dg = (tid * 8 + t == m);
        o0.u[t] = f2bf((dg ? 1.f : v0[t]) * i0);
        o1.u[t] = f2bf((dg ? 1.f : v1[t]) * i1);
        os.u[t] = f2bf((dg ? 1.f : (v0[t] + v1[t])) * is);
      }
      *(short8v*)(Hn2T + rb) = o0.v;
      *(short8v*)(Hn2T + NN + rb) = o1.v;
      *(short8v*)(HsT + rb) = os.v;
      __syncthreads();  // smem reused next virtual block
      break;
    }
    case 5: {  // P7 partials: Hn2T[c] @ XWT^T, split-K 8 (256 virtuals)
      int c = vb >> 7, s = (vb >> 4) & 7, y = vb & 15;
      bf16_gemm_body(Hn2T + (size_t)c * NN, XWT,
                     P7bf + (size_t)c * 2097152 + (size_t)s * 262144,
                     NDIM, WOUT, y * 128, 0, s * 256, s * 256 + 256,
                     (char*)smem, (char*)smem + 16384);
      break;
    }
    case 6: {  // Xcat = relu(sum partials)
      int idx = vb * 256 + tid;
      int c = idx >> 18;
      int rem = idx & 262143;
      float s = 0.f;
#pragma unroll
      for (int sp = 0; sp < 8; ++sp)
        s += __bfloat162float(P7bf[(size_t)c * 2097152 + (size_t)sp * 262144 + rem]);
      int n = rem >> 7, d = rem & 127;
      Xcat[(size_t)n * 256 + (c << 7) + d] = __float2bfloat16(fmaxf(s, 0.f));
      break;
    }
    case 7: {  // XC12T = W12Tbf @ Xcat^T (48 virtuals)
      int x = vb & 15, y = vb >> 4;
      bf16_gemm_body(W12Tbf, Xcat, XC12T, 256, NDIM, y * 128, x * 128, 0, 256,
                     (char*)smem, (char*)smem + 16384);
      break;
    }
    case 8: {  // P10 partials: HsT @ XC12T^T, split-K 8 (384 virtuals)
      int z = vb / 48, rem = vb - z * 48;
      int y = rem / 3, x = rem - y * 3;
      bf16_gemm_body(HsT, XC12T, P10bf + (size_t)z * 786432,
                     NDIM, 384, y * 128, x * 128, z * 256, z * 256 + 256,
                     (char*)smem, (char*)smem + 16384);
      break;
    }
    case 9: {  // losses + y (3072 virtuals)
      const int b = vb;
      if (b < 2048) {
        float xr = 0.f;
#pragma unroll
        for (int sp = 0; sp < 8; ++sp)
          xr += __bfloat162float(P10bf[(size_t)sp * 786432 + (size_t)b * 384 + 128 + tid]);
        if (xr > 1.f) xr = 1.f / (1.f + expf(-xr));
        if (xr < 0.f) xr = 1.f / (1.f + expf(-xr));
        float p = fminf(fmaxf(xr, 1e-7f), 1.f - 1e-7f);
        float xv = X[(size_t)b * WIN + tid];
        float t = xv * logf(p) + (1.f - xv) * log1pf(-p);
        for (int off = 32; off > 0; off >>= 1) t += __shfl_down(t, off, 64);
        float* red = (float*)smem;
        if ((tid & 63) == 0) red[tid >> 6] = t;
        __syncthreads();
        if (tid == 0) atomicAdd(acc + 1, red[0] + red[1] + red[2] + red[3]);
        __syncthreads();
        break;
      }
      const int t = b - 2048;
      float* xo = (float*)smem;        // 128
      float* ys = (float*)smem + 128;  // 8
      int x = txs[t];
      if (tid < WOUT) {
        float s = 0.f;
#pragma unroll
        for (int sp = 0; sp < 8; ++sp)
          s += __bfloat162float(P10bf[(size_t)sp * 786432 + (size_t)x * 384 + tid]);
        xo[tid] = s;
      }
      __syncthreads();
      if (tid < NCLS) {
        float s = linb[tid];
        for (int d = 0; d < WOUT; ++d) s += xo[d] * linw[tid * WOUT + d];
        ys[tid] = s;
        dout[1 + (size_t)t * NCLS + tid] = s;
      }
      __syncthreads();
      if (tid == 0) {
        float m = ys[0];
        for (int k = 1; k < NCLS; ++k) m = fmaxf(m, ys[k]);
        float se = 0.f;
        for (int k = 0; k < NCLS; ++k) se += expf(ys[k] - m);
        float lse = m + logf(se);
        atomicAdd(acc, lse - ys[tgt[t]]);
      }
      __syncthreads();
      break;
    }
    case 10: {  // finalize
      if (vb == 0 && tid == 0) {
        float lossC = acc[0] / (float)NTGT;
        float lossR = -acc[1] / (float)(NDIM * WIN);
        dout[0] = lossC + lossR;
        dout[1 + NTGT * NCLS + 30] = lossR;
      }
      break;
    }
  }
}

__device__ __constant__ const int kPhaseCounts[11] = {
    4096 + N_PREPB, 528, 4096, 512, 2048, 256, 2048, 48, 384, 3072, 1};

// ---------------------------------------------------------------------------
// cooperative mega-kernel: all phases, grid.sync() between them
// ---------------------------------------------------------------------------
__global__ __launch_bounds__(256, 2) void mega_k(
    const float* A, const float* X, const float* W, const float* W1,
    const float* W2, const float* linw, const float* linb, const float* w0a,
    const float* w0b, const float* w1a, const int* txs, const int* tgt,
    float* dout, float* ws) {
  __shared__ __align__(16) unsigned char smem[32768];
  cg::grid_group grid = cg::this_grid();
  for (int ph = 0; ph < 11; ++ph) {
    for (int vb = blockIdx.x; vb < kPhaseCounts[ph]; vb += GRID)
      phase_exec(ph, vb, smem, A, X, W, W1, W2, linw, linb, w0a, w0b, w1a,
                 txs, tgt, dout, ws);
    if (ph < 10) grid.sync();
  }
}

// fallback: one phase per launch (used only if cooperative launch fails)
__global__ __launch_bounds__(256, 2) void phase_k(
    int ph, const float* A, const float* X, const float* W, const float* W1,
    const float* W2, const float* linw, const float* linb, const float* w0a,
    const float* w0b, const float* w1a, const int* txs, const int* tgt,
    float* dout, float* ws) {
  __shared__ __align__(16) unsigned char smem[32768];
  phase_exec(ph, blockIdx.x, smem, A, X, W, W1, W2, linw, linb, w0a, w0b, w1a,
             txs, tgt, dout, ws);
}

// ---------------------------------------------------------------------------
extern "C" void kernel_launch(void* const* d_in, const int* in_sizes, int n_in,
                              void* d_out, int out_size, void* d_ws, size_t ws_size,
                              hipStream_t stream) {
  const float* A    = (const float*)d_in[0];
  const float* X    = (const float*)d_in[1];
  const float* W    = (const float*)d_in[2];
  const float* W1   = (const float*)d_in[3];
  const float* W2   = (const float*)d_in[4];
  const float* linw = (const float*)d_in[5];
  const float* linb = (const float*)d_in[6];
  const float* w0a  = (const float*)d_in[7];
  const float* w0b  = (const float*)d_in[8];
  const float* w1a  = (const float*)d_in[9];
  const int* txs    = (const int*)d_in[10];
  const int* tgt    = (const int*)d_in[11];
  float* dout = (float*)d_out;
  float* ws = (float*)d_ws;

  void* args[] = {&A, &X, &W, &W1, &W2, &linw, &linb, &w0a, &w0b, &w1a,
                  &txs, &tgt, &dout, &ws};
  hipError_t err = hipLaunchCooperativeKernel((const void*)mega_k, dim3(GRID),
                                              dim3(256), args, 0, stream);
  if (err != hipSuccess) {
    const int counts[11] = {4096 + N_PREPB, 528, 4096, 512, 2048, 256, 2048,
                            48, 384, 3072, 1};
    for (int ph = 0; ph < 11; ++ph)
      phase_k<<<dim3(counts[ph]), dim3(256), 0, stream>>>(
          ph, A, X, W, W1, W2, linw, linb, w0a, w0b, w1a, txs, tgt, dout, ws);
  }
}

// Round 12
// 279.805 us; speedup vs baseline: 3.6833x; 3.6833x over previous
//
#include <hip/hip_runtime.h>
#include <hip/hip_bf16.h>
#include <math.h>

#define NDIM 2048
#define EDIM 5
#define CDIM 2
#define WIN 256
#define WOUT 128
#define NCLS 8
#define NTGT 1024
#define NN ((size_t)NDIM * NDIM)
#define HNSC 256.0f          // Hn stored as fp8 * HNSC (raw ~5e-4 underflows e4m3)
#define HNSCI 0.00390625f    // 1/HNSC

typedef __attribute__((ext_vector_type(8))) short short8v;
typedef __attribute__((ext_vector_type(4))) float float4v;
typedef __attribute__((ext_vector_type(8))) int int8v;
typedef __attribute__((ext_vector_type(4))) int int4v;
typedef __attribute__((ext_vector_type(2))) int int2v;

__device__ __forceinline__ void gl2lds16(const void* g, void* l) {
  __builtin_amdgcn_global_load_lds((__attribute__((address_space(1))) const unsigned int*)g,
                                   (__attribute__((address_space(3))) unsigned int*)l, 16, 0, 0);
}
__device__ __forceinline__ float bf2f(unsigned short u) {
  return __uint_as_float(((unsigned)u) << 16);
}
__device__ __forceinline__ unsigned short f2bf(float f) {
  __hip_bfloat16 h = __float2bfloat16(f);
  return *(unsigned short*)&h;
}
__device__ __forceinline__ unsigned int pk4fp8(float a, float b, float c, float d) {
  int w = __builtin_amdgcn_cvt_pk_fp8_f32(a, b, 0, false);
  return (unsigned int)__builtin_amdgcn_cvt_pk_fp8_f32(c, d, w, true);
}

// ---------------------------------------------------------------------------
// mega setup. blocks < 4096: 32x32 tile of A -> a, bT, a1T (fp8, packed dword
// stores, float4 loads). blocks >= 4096: Xbf/WTbf/W12Tbf bf16, zero deg/acc,
// Ws softmax outputs.
// ---------------------------------------------------------------------------
#define N_XBF (NDIM * WIN)          // 524288
#define N_WT (WIN * WOUT)           // 32768
#define N_W12T (384 * WIN)          // 98304
#define N_PREP (N_XBF + N_WT + N_W12T + CDIM * NDIM + 16 + 30)
__global__ __launch_bounds__(256) void wsum_mega_k(
    const float* __restrict__ A, const float* __restrict__ w0a,
    const float* __restrict__ w0b, const float* __restrict__ w1a,
    unsigned char* __restrict__ a_out, unsigned char* __restrict__ bT,
    unsigned char* __restrict__ a1T,
    float* __restrict__ acc, float* __restrict__ deg,
    const float* __restrict__ X, const float* __restrict__ W,
    const float* __restrict__ W1, const float* __restrict__ W2,
    __hip_bfloat16* __restrict__ Xbf, __hip_bfloat16* __restrict__ WTbf,
    __hip_bfloat16* __restrict__ W12Tbf,
    float* __restrict__ dout) {
  const int b = blockIdx.x;
  const int tid = threadIdx.x;
  if (b >= 4096) {
    int idx = (b - 4096) * 256 + tid;
    if (idx < N_XBF) { Xbf[idx] = __float2bfloat16(X[idx]); return; }
    idx -= N_XBF;
    if (idx < N_WT) {
      int d = idx >> 8, k = idx & 255;
      WTbf[idx] = __float2bfloat16(W[k * WOUT + d]);
      return;
    }
    idx -= N_WT;
    if (idx < N_W12T) {
      int j = idx >> 8, k = idx & 255;
      W12Tbf[idx] = __float2bfloat16(j < 128 ? W1[k * 128 + j] : W2[k * 256 + (j - 128)]);
      return;
    }
    idx -= N_W12T;
    if (idx < CDIM * NDIM) { deg[idx] = 0.f; return; }
    idx -= CDIM * NDIM;
    if (idx < 16) { acc[idx] = 0.f; return; }
    idx -= 16;
    if (idx < 30) {
      int m = idx / 10, rr = idx - m * 10, c = rr / 5, e = rr - c * 5;
      const float* src = (m == 0) ? w0a : (m == 1) ? w0b : w1a;
      float mx = -1e30f;
      for (int t = 0; t < 5; ++t) mx = fmaxf(mx, src[c * 5 + t]);
      float s = 0.f, ve = 0.f;
      for (int t = 0; t < 5; ++t) {
        float ex = expf(src[c * 5 + t] - mx);
        s += ex;
        if (t == e) ve = ex;
      }
      dout[1 + NTGT * NCLS + idx] = ve / s;
    }
    return;
  }
  __shared__ float swl[32];
  __shared__ float tb[CDIM][32][33];
  __shared__ float tc[CDIM][32][33];
  if (tid < 6) {
    int m = tid >> 1, c = tid & 1;
    const float* src = (m == 0) ? w0a : (m == 1) ? w0b : w1a;
    float mx = -1e30f;
    for (int e = 0; e < 5; ++e) mx = fmaxf(mx, src[c * 5 + e]);
    float ex[5]; float s = 0.f;
    for (int e = 0; e < 5; ++e) { ex[e] = expf(src[c * 5 + e] - mx); s += ex[e]; }
    for (int e = 0; e < 5; ++e) swl[m * 10 + c * 5 + e] = ex[e] / s;
  }
  __syncthreads();
  const int bx = (b & 63) * 32, by = (b >> 6) * 32;
  const int tx4 = tid & 7, ty = tid >> 3;
  const int n = by + ty, m0 = bx + tx4 * 4;
  const float* ap = A + ((size_t)n * NDIM + m0) * EDIM;
  float4 f0 = *(const float4*)(ap);
  float4 f1 = *(const float4*)(ap + 4);
  float4 f2 = *(const float4*)(ap + 8);
  float4 f3 = *(const float4*)(ap + 12);
  float4 f4 = *(const float4*)(ap + 16);
  float v[4][5] = {{f0.x, f0.y, f0.z, f0.w, f1.x},
                   {f1.y, f1.z, f1.w, f2.x, f2.y},
                   {f2.z, f2.w, f3.x, f3.y, f3.z},
                   {f3.w, f4.x, f4.y, f4.z, f4.w}};
#pragma unroll
  for (int c = 0; c < CDIM; ++c) {
    float sa[4], sb[4], sc[4];
#pragma unroll
    for (int t = 0; t < 4; ++t) {
      sa[t] = swl[c*5]*v[t][0] + swl[c*5+1]*v[t][1] + swl[c*5+2]*v[t][2] +
              swl[c*5+3]*v[t][3] + swl[c*5+4]*v[t][4];
      sb[t] = swl[10+c*5]*v[t][0] + swl[10+c*5+1]*v[t][1] + swl[10+c*5+2]*v[t][2] +
              swl[10+c*5+3]*v[t][3] + swl[10+c*5+4]*v[t][4];
      sc[t] = swl[20+c*5]*v[t][0] + swl[20+c*5+1]*v[t][1] + swl[20+c*5+2]*v[t][2] +
              swl[20+c*5+3]*v[t][3] + swl[20+c*5+4]*v[t][4];
      tb[c][ty][tx4 * 4 + t] = sb[t];
      tc[c][ty][tx4 * 4 + t] = sc[t];
    }
    *(unsigned int*)(a_out + c * NN + (size_t)n * NDIM + m0) =
        pk4fp8(sa[0], sa[1], sa[2], sa[3]);
  }
  __syncthreads();
  const int mm = bx + ty, nn0 = by + tx4 * 4;
#pragma unroll
  for (int c = 0; c < CDIM; ++c) {
    float b0 = tb[c][tx4*4+0][ty], b1 = tb[c][tx4*4+1][ty];
    float b2 = tb[c][tx4*4+2][ty], b3 = tb[c][tx4*4+3][ty];
    float c0 = tc[c][tx4*4+0][ty], c1 = tc[c][tx4*4+1][ty];
    float c2 = tc[c][tx4*4+2][ty], c3 = tc[c][tx4*4+3][ty];
    *(unsigned int*)(bT + c * NN + (size_t)mm * NDIM + nn0) = pk4fp8(b0, b1, b2, b3);
    *(unsigned int*)(a1T + c * NN + (size_t)mm * NDIM + nn0) = pk4fp8(c0, c1, c2, c3);
  }
}

// ---------------------------------------------------------------------------
// fp8 GEMM body, DOUBLE-BUFFERED LDS (2 x 32 KB), ONE barrier per K-iter.
// ---------------------------------------------------------------------------
__device__ __forceinline__ void fp8_stage(const unsigned char* __restrict__ A,
                                          const unsigned char* __restrict__ B,
                                          int K, int row0, int col0, int k0,
                                          int wave, int srow, int scol,
                                          unsigned char* As, unsigned char* Bs) {
#pragma unroll
  for (int s = 0; s < 4; ++s) {
    gl2lds16(A + (size_t)(row0 + s * 32 + wave * 8 + srow) * K + k0 + scol,
             As + s * 4096 + wave * 1024);
    gl2lds16(B + (size_t)(col0 + s * 32 + wave * 8 + srow) * K + k0 + scol,
             Bs + s * 4096 + wave * 1024);
  }
}

__device__ __forceinline__ void fp8_gemm_body(
    const unsigned char* __restrict__ A, const unsigned char* __restrict__ B,
    __hip_bfloat16* __restrict__ Cp, float* __restrict__ csp,
    int K, int ldc, int row0, int col0, unsigned char* smem) {
  const int tid = threadIdx.x;
  const int lane = tid & 63;
  const int wave = tid >> 6;
  const int wr = (wave >> 1) * 64;
  const int wc = (wave & 1) * 64;
  const int q = lane >> 4;
  const int r = lane & 15;

  float4v acc[4][4] = {};

  const int srow = lane >> 3;
  const int scol = ((lane & 7) ^ (srow & 7)) * 16;
  const int fsw = r & 7;

  unsigned char* As[2] = {smem, smem + 32768};
  unsigned char* Bs[2] = {smem + 16384, smem + 49152};

  fp8_stage(A, B, K, row0, col0, 0, wave, srow, scol, As[0], Bs[0]);
  __syncthreads();

  int p = 0;
  for (int k0 = 0; k0 < K; k0 += 128, p ^= 1) {
    if (k0 + 128 < K)
      fp8_stage(A, B, K, row0, col0, k0 + 128, wave, srow, scol, As[p ^ 1], Bs[p ^ 1]);

    union { int8v v; int4v h[2]; } ua[4], ub[4];
#pragma unroll
    for (int i = 0; i < 4; ++i) {
      const unsigned char* pa = As[p] + (size_t)(wr + i * 16 + r) * 128;
      const unsigned char* pb = Bs[p] + (size_t)(wc + i * 16 + r) * 128;
      ua[i].h[0] = *(const int4v*)(pa + (((2 * q) ^ fsw) * 16));
      ua[i].h[1] = *(const int4v*)(pa + (((2 * q + 1) ^ fsw) * 16));
      ub[i].h[0] = *(const int4v*)(pb + (((2 * q) ^ fsw) * 16));
      ub[i].h[1] = *(const int4v*)(pb + (((2 * q + 1) ^ fsw) * 16));
    }
#pragma unroll
    for (int i = 0; i < 4; ++i)
#pragma unroll
      for (int j = 0; j < 4; ++j)
        acc[i][j] = __builtin_amdgcn_mfma_scale_f32_16x16x128_f8f6f4(
            ua[i].v, ub[j].v, acc[i][j], 0, 0, 0, 0x7F7F7F7F, 0, 0x7F7F7F7F);
    __syncthreads();  // waves done reading As[p]/Bs[p]; k+1 loads drained
  }

#pragma unroll
  for (int i = 0; i < 4; ++i) {
    int row = row0 + wr + i * 16 + q * 4;
#pragma unroll
    for (int j = 0; j < 4; ++j) {
      int col = col0 + wc + j * 16 + r;
#pragma unroll
      for (int e = 0; e < 4; ++e)
        Cp[(size_t)(row + e) * ldc + col] = __float2bfloat16(acc[i][j][e]);
    }
  }

  if (csp) {
#pragma unroll
    for (int j = 0; j < 4; ++j) {
      int col = col0 + wc + j * 16 + r;
      float s = 0.f;
#pragma unroll
      for (int i = 0; i < 4; ++i) {
        int rowb = row0 + wr + i * 16 + q * 4;
#pragma unroll
        for (int e = 0; e < 4; ++e)
          if (rowb + e != col) s += acc[i][j][e];
      }
      s += __shfl_xor(s, 16, 64);
      s += __shfl_xor(s, 32, 64);
      if (lane < 16) atomicAdd(&csp[col], s);
    }
  }
}

// ---------------------------------------------------------------------------
// bf16 GEMM body (B^T input, 128x128 tile, BK=64, swizzled, bf16 out)
// ---------------------------------------------------------------------------
__device__ __forceinline__ void bf16_gemm_body(
    const __hip_bfloat16* __restrict__ A, const __hip_bfloat16* __restrict__ B,
    __hip_bfloat16* __restrict__ Cp, int K, int ldc, int row0, int col0,
    int kbeg, int kend, char* As, char* Bs) {
  const int tid = threadIdx.x;
  const int lane = tid & 63;
  const int wave = tid >> 6;
  const int wr = (wave >> 1) * 64;
  const int wc = (wave & 1) * 64;
  const int q = lane >> 4;
  const int r = lane & 15;

  float4v acc[4][4] = {};

  const int srow = lane >> 3;
  const int scol = ((lane & 7) ^ (srow & 7)) * 8;
  const int fsw = r & 7;

  for (int k0 = kbeg; k0 < kend; k0 += 64) {
    __syncthreads();
#pragma unroll
    for (int s = 0; s < 4; ++s) {
      gl2lds16(A + (size_t)(row0 + s * 32 + wave * 8 + srow) * K + k0 + scol,
               As + s * 4096 + wave * 1024);
      gl2lds16(B + (size_t)(col0 + s * 32 + wave * 8 + srow) * K + k0 + scol,
               Bs + s * 4096 + wave * 1024);
    }
    __syncthreads();
#pragma unroll
    for (int h = 0; h < 2; ++h) {
      short8v af[4], bf[4];
#pragma unroll
      for (int i = 0; i < 4; ++i) {
        af[i] = *(const short8v*)(As + (size_t)(wr + i * 16 + r) * 128 +
                                  (((h * 4 + q) ^ fsw) * 16));
        bf[i] = *(const short8v*)(Bs + (size_t)(wc + i * 16 + r) * 128 +
                                  (((h * 4 + q) ^ fsw) * 16));
      }
#pragma unroll
      for (int i = 0; i < 4; ++i)
#pragma unroll
        for (int j = 0; j < 4; ++j)
          acc[i][j] = __builtin_amdgcn_mfma_f32_16x16x32_bf16(af[i], bf[j], acc[i][j], 0, 0, 0);
    }
  }

#pragma unroll
  for (int i = 0; i < 4; ++i) {
    int row = row0 + wr + i * 16 + q * 4;
#pragma unroll
    for (int j = 0; j < 4; ++j) {
      int col = col0 + wc + j * 16 + r;
#pragma unroll
      for (int e = 0; e < 4; ++e)
        Cp[(size_t)(row + e) * ldc + col] = __float2bfloat16(acc[i][j][e]);
    }
  }
}

// ---------------------------------------------------------------------------
// combined launch: z<2 -> GEMM1 batch z (H = a@b, fp8 dbuf, col sums);
// z==2,y==0 -> XWT[128][2048] = WTbf @ Xbf^T (bf16, K=256).
// ---------------------------------------------------------------------------
__global__ __launch_bounds__(256) void gemm1_xwt_k(
    const unsigned char* __restrict__ P_a, const unsigned char* __restrict__ P_bT,
    __hip_bfloat16* __restrict__ H_bf, float* __restrict__ deg,
    const __hip_bfloat16* __restrict__ WTbf, const __hip_bfloat16* __restrict__ Xbf,
    __hip_bfloat16* __restrict__ XWT) {
  __shared__ __align__(16) unsigned char smem[65536];
  const int z = blockIdx.z;
  if (z < 2) {
    fp8_gemm_body(P_a + (size_t)z * NN, P_bT + (size_t)z * NN,
                  H_bf + (size_t)z * NN, deg + (size_t)z * NDIM,
                  NDIM, NDIM, blockIdx.y * 128, blockIdx.x * 128, smem);
  } else {
    if (blockIdx.y != 0) return;
    bf16_gemm_body(WTbf, Xbf, XWT, WIN, NDIM, 0, blockIdx.x * 128,
                   0, WIN, (char*)smem, (char*)smem + 16384);
  }
}

// GEMM2: H1T*HNSC = a1T @ (Hn*HNSC)^T, fp8 dbuf, no col sums
__global__ __launch_bounds__(256) void gemm2_k(
    const unsigned char* __restrict__ P_a1T, const unsigned char* __restrict__ P_Hn,
    __hip_bfloat16* __restrict__ H1T_bf) {
  __shared__ __align__(16) unsigned char smem[65536];
  const int z = blockIdx.z;
  fp8_gemm_body(P_a1T + (size_t)z * NN, P_Hn + (size_t)z * NN,
                H1T_bf + (size_t)z * NN, nullptr,
                NDIM, NDIM, blockIdx.y * 128, blockIdx.x * 128, smem);
}

// bf16 tail GEMM: out bf16 at batch*sC + split*sSplit (bf16 elems)
__global__ __launch_bounds__(256) void mfma_bt_k(
    const __hip_bfloat16* __restrict__ Ab, const __hip_bfloat16* __restrict__ Bt,
    __hip_bfloat16* __restrict__ Cv, int K, int ldc,
    size_t sA, size_t sB, size_t sC, size_t sSplit, int nsplit) {
  __shared__ __align__(16) char smem[32768];
  const int batch = blockIdx.z / nsplit;
  const int split = blockIdx.z - batch * nsplit;
  const int kchunk = K / nsplit;
  bf16_gemm_body(Ab + (size_t)batch * sA, Bt + (size_t)batch * sB,
                 Cv + (size_t)batch * sC + (size_t)split * sSplit,
                 K, ldc, blockIdx.y * 128, blockIdx.x * 128,
                 split * kchunk, split * kchunk + kchunk,
                 smem, smem + 16384);
}

// ---------------------------------------------------------------------------
// Hn = norm(H, add=False): zero diag, col j scaled by HNSC/deg[j], fp8 out.
// ---------------------------------------------------------------------------
__global__ __launch_bounds__(256) void col_scale_k(const __hip_bfloat16* __restrict__ H,
                                                   const float* __restrict__ deg,
                                                   unsigned char* __restrict__ out) {
  size_t base = ((size_t)blockIdx.x * 256 + threadIdx.x) * 8;  // over 2*NN
  int c = (int)(base >> 22);
  int i = (int)((base >> 11) & (NDIM - 1));
  int j0 = (int)(base & (NDIM - 1));
  union { short8v v; unsigned short u[8]; } p;
  p.v = *(const short8v*)(H + base);
  float f[8];
#pragma unroll
  for (int t = 0; t < 8; ++t) {
    int j = j0 + t;
    float d = deg[c * NDIM + j];
    float inv = (d == 0.f) ? 0.f : HNSC / d;
    float v = (i == j) ? 0.f : bf2f(p.u[t]);
    f[t] = v * inv;
  }
  int2v o;
  o.x = (int)pk4fp8(f[0], f[1], f[2], f[3]);
  o.y = (int)pk4fp8(f[4], f[5], f[6], f[7]);
  *(int2v*)(out + base) = o;
}

// ---------------------------------------------------------------------------
// row norms over H1T (2ch bf16, values *HNSC): Hn2T[0], Hn2T[1], HsT bf16
// ---------------------------------------------------------------------------
__global__ __launch_bounds__(256) void rowmega_k(const __hip_bfloat16* __restrict__ H1T,
                                                 __hip_bfloat16* __restrict__ Hn2T,
                                                 __hip_bfloat16* __restrict__ HsT) {
  const int m = blockIdx.x;
  const int tid = threadIdx.x;
  const size_t rb = (size_t)m * NDIM + tid * 8;
  union { short8v v; unsigned short u[8]; } a0, a1;
  a0.v = *(const short8v*)(H1T + rb);
  a1.v = *(const short8v*)(H1T + NN + rb);
  float v0[8], v1[8];
  float s0 = 0.f, s1 = 0.f;
#pragma unroll
  for (int t = 0; t < 8; ++t) {
    v0[t] = bf2f(a0.u[t]) * HNSCI;
    v1[t] = bf2f(a1.u[t]) * HNSCI;
    s0 += v0[t]; s1 += v1[t];
  }
  __shared__ float ds[2];
  __shared__ float red[2][4];
  __shared__ float bc[3];
  if (tid == (m >> 3)) { ds[0] = v0[m & 7]; ds[1] = v1[m & 7]; }
  for (int off = 32; off > 0; off >>= 1) {
    s0 += __shfl_down(s0, off, 64);
    s1 += __shfl_down(s1, off, 64);
  }
  if ((tid & 63) == 0) { red[0][tid >> 6] = s0; red[1][tid >> 6] = s1; }
  __syncthreads();
  if (tid == 0) {
    float t0 = red[0][0] + red[0][1] + red[0][2] + red[0][3];
    float t1 = red[1][0] + red[1][1] + red[1][2] + red[1][3];
    float r0 = t0 - ds[0] + 1.f;
    float r1 = t1 - ds[1] + 1.f;
    float rs = t0 + t1 - ds[0] - ds[1] + 1.f;
    bc[0] = (r0 == 0.f) ? 0.f : 1.f / r0;
    bc[1] = (r1 == 0.f) ? 0.f : 1.f / r1;
    bc[2] = (rs == 0.f) ? 0.f : 1.f / rs;
  }
  __syncthreads();
  float i0 = bc[0], i1 = bc[1], is = bc[2];
  union { short8v v; unsigned short u[8]; } o0, o1, os;
#pragma unroll
  for (int t = 0; t < 8; ++t) {
    bool dg = (tid * 8 + t == m);
    o0.u[t] = f2bf((dg ? 1.f : v0[t]) * i0);
    o1.u[t] = f2bf((dg ? 1.f : v1[t]) * i1);
    os.u[t] = f2bf((dg ? 1.f : (v0[t] + v1[t])) * is);
  }
  *(short8v*)(Hn2T + rb) = o0.v;
  *(short8v*)(Hn2T + NN + rb) = o1.v;
  *(short8v*)(HsT + rb) = os.v;
}

// ---------------------------------------------------------------------------
// Xcat[n][c*128+d] = relu(sum_s P7[c][s][n][d])  (8 bf16 partials -> bf16)
// ---------------------------------------------------------------------------
__global__ __launch_bounds__(256) void reduce_relu_k(const __hip_bfloat16* __restrict__ P7,
                                                     __hip_bfloat16* __restrict__ Xcat) {
  int idx = blockIdx.x * 256 + threadIdx.x;  // 524288
  int c = idx >> 18;
  int rem = idx & 262143;
  float s = 0.f;
#pragma unroll
  for (int sp = 0; sp < 8; ++sp)
    s += __bfloat162float(P7[(size_t)c * 2097152 + (size_t)sp * 262144 + rem]);
  int n = rem >> 7, d = rem & 127;
  Xcat[(size_t)n * 256 + (c << 7) + d] = __float2bfloat16(fmaxf(s, 0.f));
}

// ---------------------------------------------------------------------------
// blocks [0,2048): BCE loss row n (sums 8 bf16 partials, cols 128..384).
// blocks [2048,3072): y + class loss (cols 0..128).
// ---------------------------------------------------------------------------
__global__ __launch_bounds__(256) void loss_mega_k(const __hip_bfloat16* __restrict__ P10,
                                                   const float* __restrict__ X,
                                                   const float* __restrict__ lin_w,
                                                   const float* __restrict__ lin_b,
                                                   const int* __restrict__ txs,
                                                   const int* __restrict__ tgt,
                                                   float* __restrict__ yout,
                                                   float* __restrict__ acc) {
  const int b = blockIdx.x;
  const int tid = threadIdx.x;
  if (b < 2048) {
    float xr = 0.f;
#pragma unroll
    for (int sp = 0; sp < 8; ++sp)
      xr += __bfloat162float(P10[(size_t)sp * 786432 + (size_t)b * 384 + 128 + tid]);
    if (xr > 1.f) xr = 1.f / (1.f + expf(-xr));
    if (xr < 0.f) xr = 1.f / (1.f + expf(-xr));
    float p = fminf(fmaxf(xr, 1e-7f), 1.f - 1e-7f);
    float xv = X[(size_t)b * WIN + tid];
    float t = xv * logf(p) + (1.f - xv) * log1pf(-p);
    for (int off = 32; off > 0; off >>= 1) t += __shfl_down(t, off, 64);
    __shared__ float red[4];
    if ((tid & 63) == 0) red[tid >> 6] = t;
    __syncthreads();
    if (tid == 0) atomicAdd(acc + 1, red[0] + red[1] + red[2] + red[3]);
    return;
  }
  const int t = b - 2048;
  __shared__ float xo[WOUT];
  __shared__ float ys[NCLS];
  int x = txs[t];
  if (tid < WOUT) {
    float s = 0.f;
#pragma unroll
    for (int sp = 0; sp < 8; ++sp)
      s += __bfloat162float(P10[(size_t)sp * 786432 + (size_t)x * 384 + tid]);
    xo[tid] = s;
  }
  __syncthreads();
  if (tid < NCLS) {
    float s = lin_b[tid];
    for (int d = 0; d < WOUT; ++d) s += xo[d] * lin_w[tid * WOUT + d];
    ys[tid] = s;
    yout[(size_t)t * NCLS + tid] = s;
  }
  __syncthreads();
  if (tid == 0) {
    float m = ys[0];
    for (int k = 1; k < NCLS; ++k) m = fmaxf(m, ys[k]);
    float se = 0.f;
    for (int k = 0; k < NCLS; ++k) se += expf(ys[k] - m);
    float lse = m + logf(se);
    atomicAdd(acc, lse - ys[tgt[t]]);
  }
}

__global__ void finalize_k(const float* __restrict__ acc, float* __restrict__ dout) {
  float lossC = acc[0] / (float)NTGT;
  float lossR = -acc[1] / (float)(NDIM * WIN);
  dout[0] = lossC + lossR;
  dout[1 + NTGT * NCLS + 30] = lossR;
}

// ---------------------------------------------------------------------------
extern "C" void kernel_launch(void* const* d_in, const int* in_sizes, int n_in,
                              void* d_out, int out_size, void* d_ws, size_t ws_size,
                              hipStream_t stream) {
  const float* A    = (const float*)d_in[0];
  const float* X    = (const float*)d_in[1];
  const float* W    = (const float*)d_in[2];
  const float* W1   = (const float*)d_in[3];
  const float* W2   = (const float*)d_in[4];
  const float* linw = (const float*)d_in[5];
  const float* linb = (const float*)d_in[6];
  const float* w0a  = (const float*)d_in[7];
  const float* w0b  = (const float*)d_in[8];
  const float* w1a  = (const float*)d_in[9];
  const int* txs    = (const int*)d_in[10];
  const int* tgt    = (const int*)d_in[11];
  float* dout = (float*)d_out;

  float* ws = (float*)d_ws;
  unsigned char* wb = (unsigned char*)d_ws;
  unsigned char* P_a   = wb;
  unsigned char* P_bT  = wb + 2 * NN;
  unsigned char* P_a1T = wb + 4 * NN;
  unsigned char* P_Hn  = wb + 6 * NN;
  __hip_bfloat16* H_bf   = (__hip_bfloat16*)(ws + 2 * NN);  // H (2ch)
  __hip_bfloat16* H1T_bf = (__hip_bfloat16*)(ws + 3 * NN);  // H1T*HNSC (2ch)
  __hip_bfloat16* Hn2T   = (__hip_bfloat16*)(ws + 4 * NN);  // (2ch)
  __hip_bfloat16* HsT    = (__hip_bfloat16*)(ws);           // 1ch, overlays dead fp8 a/bT
  float* sm   = ws + 5 * NN;
  float* acc   = sm;                 sm += 16;
  float* deg   = sm;                 sm += CDIM * NDIM;
  __hip_bfloat16* Xbf    = (__hip_bfloat16*)sm;  sm += N_XBF / 2;
  __hip_bfloat16* WTbf   = (__hip_bfloat16*)sm;  sm += N_WT / 2;
  __hip_bfloat16* W12Tbf = (__hip_bfloat16*)sm;  sm += N_W12T / 2;
  __hip_bfloat16* XWT    = (__hip_bfloat16*)sm;  sm += (size_t)WOUT * NDIM / 2;
  __hip_bfloat16* Xcat   = (__hip_bfloat16*)sm;  sm += (size_t)NDIM * 256 / 2;
  __hip_bfloat16* XC12T  = (__hip_bfloat16*)sm;  sm += (size_t)384 * NDIM / 2;
  __hip_bfloat16* P7bf   = (__hip_bfloat16*)sm;  sm += (size_t)16 * 262144 / 2; // [c][s][2048][128]
  __hip_bfloat16* P10bf  = (__hip_bfloat16*)sm;  sm += (size_t)8 * 786432 / 2;  // [s][2048][384]

  dim3 blk256(256);

  // 1. fused setup: a/bT/a1T fp8 + Xbf/WTbf/W12Tbf + deg/acc zero + Ws
  wsum_mega_k<<<dim3(4096 + (N_PREP + 255) / 256), blk256, 0, stream>>>(
      A, w0a, w0b, w1a, P_a, P_bT, P_a1T, acc, deg, X, W, W1, W2,
      Xbf, WTbf, W12Tbf, dout);
  // 2. GEMM1 (H, col sums, dbuf) + XWT GEMM in one launch
  gemm1_xwt_k<<<dim3(16, 16, 3), blk256, 0, stream>>>(P_a, P_bT, H_bf, deg,
                                                      WTbf, Xbf, XWT);
  // 3. Hn*HNSC = colscale(H) -> fp8
  col_scale_k<<<dim3((unsigned)(2 * NN / 2048)), blk256, 0, stream>>>(H_bf, deg, P_Hn);
  // 4. H1T*HNSC = a1T @ (Hn*HNSC)^T -> bf16 (dbuf)
  gemm2_k<<<dim3(16, 16, 2), blk256, 0, stream>>>(P_a1T, P_Hn, H1T_bf);
  // 5. row norms (descale 1/HNSC): Hn2T (2ch), HsT
  rowmega_k<<<dim3(NDIM), blk256, 0, stream>>>(H1T_bf, Hn2T, HsT);
  // 6. Xc partials: P7bf[c][s] = Hn2T[c] @ XWT^T (split-K 8, bf16 partials)
  mfma_bt_k<<<dim3(1, 16, 16), blk256, 0, stream>>>(Hn2T, XWT, P7bf, NDIM, WOUT,
                                                    NN, 0, 2097152, 262144, 8);
  // 7. Xcat bf16 = relu(sum partials)
  reduce_relu_k<<<dim3(2048), blk256, 0, stream>>>(P7bf, Xcat);
  // 8. XC12T[384][2048] = W12Tbf @ Xcat^T
  mfma_bt_k<<<dim3(16, 3, 1), blk256, 0, stream>>>(W12Tbf, Xcat, XC12T, 256, NDIM,
                                                   0, 0, 0, 0, 1);
  // 9. XoXr partials: P10bf[s] = HsT @ XC12T^T (split-K 8, bf16 partials)
  mfma_bt_k<<<dim3(3, 16, 8), blk256, 0, stream>>>(HsT, XC12T, P10bf, NDIM, 384,
                                                   0, 0, 0, 786432, 8);
  // 10. losses + y (sums P10 partials inline)
  loss_mega_k<<<dim3(2048 + NTGT), blk256, 0, stream>>>(P10bf, X, linw, linb, txs, tgt,
                                                        dout + 1, acc);
  finalize_k<<<dim3(1), dim3(1), 0, stream>>>(acc, dout);
}